// Round 2
// baseline (953.509 us; speedup 1.0000x reference)
//
#include <hip/hip_runtime.h>
#include <stdint.h>

typedef unsigned int u32;
typedef unsigned long long u64;

#define HH 256
#define WW 512
#define HW (HH*WW)          // 131072
#define N2 (2*HW)           // 262144 per branch
#define NT (2*N2)           // 524288 total boxes
#define TOPK 4096
#define SCORE_THR 0.2f
#define NMS_THR 0.15f

// ---- workspace layout (bytes) ----
// keys region (2 MB) is reused as the NMS suppression mask (4096*64 u64 = 2 MB)
#define OFF_KEYS   0ull
#define OFF_CAND   ((size_t)NT*4)                 // u64[8192]  @ 2,097,152
#define OFF_HIST1  (OFF_CAND + 8192*8)            // u32[1024]  @ 2,162,688
#define OFF_HIST2  (OFF_HIST1 + 4096)             // u32[1024]
#define OFF_CNT    (OFF_HIST2 + 4096)             // u32 (+pad to 16B)
#define OFF_PIVOT  (OFF_CNT + 16)                 // u32[4]
#define OFF_SELIDX (OFF_PIVOT + 16)               // u32[4096]
#define OFF_SELSC  (OFF_SELIDX + (size_t)TOPK*4)  // f32[4096]
#define OFF_STAND  (OFF_SELSC + (size_t)TOPK*4)   // float4[4096] (16B aligned)
#define ZERO_BYTES (4096 + 4096 + 16)             // hist1+hist2+cnt

// orderable key for float (descending sortable as unsigned)
__device__ __forceinline__ u32 f2ord(float f) {
    u32 b = __float_as_uint(f);
    return (b & 0x80000000u) ? ~b : (b | 0x80000000u);
}

// ---------------- K1: scores -> keys + level-1 histogram ----------------
__global__ void __launch_bounds__(1024) k_keys(const float* __restrict__ psm_v,
                                               const float* __restrict__ psm_i,
                                               u32* __restrict__ keys,
                                               u32* __restrict__ hist1) {
    __shared__ u32 lh[1024];
    int t = threadIdx.x;
    lh[t] = 0;
    __syncthreads();
    int n = blockIdx.x * 1024 + t;
    int br = n >> 18;
    int m  = n & (N2 - 1);
    int a  = m & 1;
    int hw = m >> 1;
    const float* psm = br ? psm_i : psm_v;
    float x = psm[a * HW + hw];
    float s = 1.0f / (1.0f + __builtin_expf(-x));   // mirror ref f32 sigmoid
    u32 key = 0u;                                    // masked (-1.0) entries: key 0, tie->index
    if (s > SCORE_THR) key = f2ord(s);
    keys[n] = key;
    atomicAdd(&lh[key >> 22], 1u);
    __syncthreads();
    u32 c = lh[t];
    if (c) atomicAdd(&hist1[t], c);
}

// ---------------- pivot scan (suffix sums over 1024 bins) ----------------
__global__ void __launch_bounds__(1024) k_pivot(const u32* __restrict__ hist,
                                                u32* __restrict__ pivot, int mode) {
    __shared__ u32 sh[1024];
    int t = threadIdx.x;
    sh[t] = hist[t];
    __syncthreads();
    for (int off = 1; off < 1024; off <<= 1) {
        u32 add = (t + off < 1024) ? sh[t + off] : 0u;
        __syncthreads();
        sh[t] += add;
        __syncthreads();
    }
    u32 target = (mode == 0) ? (u32)TOPK : pivot[2];
    u32 Sb = sh[t];
    u32 Sn = (t < 1023) ? sh[t + 1] : 0u;
    if (Sb >= target && (t == 1023 || Sn < target)) {  // unique writer
        if (mode == 0) {
            pivot[0] = (u32)t;          // level-1 pivot bin
            pivot[2] = target - Sn;     // rank needed inside the bin
        } else {
            pivot[3] = (pivot[0] << 10) | (u32)t;  // 20-bit threshold on key>>12
        }
    }
}

// ---------------- K3: level-2 histogram inside pivot bin ----------------
__global__ void __launch_bounds__(1024) k_hist2(const u32* __restrict__ keys,
                                                const u32* __restrict__ pivot,
                                                u32* __restrict__ hist2) {
    __shared__ u32 lh[1024];
    int t = threadIdx.x;
    lh[t] = 0;
    __syncthreads();
    u32 b1 = pivot[0];
    int n = blockIdx.x * 1024 + t;
    u32 key = keys[n];
    if ((key >> 22) == b1) atomicAdd(&lh[(key >> 12) & 1023u], 1u);
    __syncthreads();
    u32 c = lh[t];
    if (c) atomicAdd(&hist2[t], c);
}

// ---------------- K5: compact candidates >= threshold ----------------
__global__ void __launch_bounds__(1024) k_collect(const u32* __restrict__ keys,
                                                  const u32* __restrict__ pivot,
                                                  u64* __restrict__ cand,
                                                  u32* __restrict__ cnt) {
    int n = blockIdx.x * 1024 + threadIdx.x;
    u32 key = keys[n];
    u32 thr = pivot[3];
    if ((key >> 12) >= thr) {
        u32 pos = atomicAdd(cnt, 1u);
        if (pos < 8192u) cand[pos] = ((u64)key << 32) | (u64)(u32)(~(u32)n);
    }
}

// ---------------- K6: single-block bitonic sort (descending) ----------------
__global__ void __launch_bounds__(1024) k_sort(const u64* __restrict__ cand,
                                               const u32* __restrict__ cnt,
                                               u32* __restrict__ sel_idx) {
    __shared__ u64 sm[8192];   // 64 KB
    int t = threadIdx.x;
    u32 c = *cnt;
    if (c > 8192u) c = 8192u;
    for (int i = t; i < 8192; i += 1024) sm[i] = (i < (int)c) ? cand[i] : 0ull;
    __syncthreads();
    for (int k = 2; k <= 8192; k <<= 1) {
        for (int j = k >> 1; j > 0; j >>= 1) {
            for (int i = t; i < 8192; i += 1024) {
                int l = i ^ j;
                if (l > i) {
                    u64 A = sm[i], B = sm[l];
                    bool desc = ((i & k) == 0);
                    if (desc ? (A < B) : (A > B)) { sm[i] = B; sm[l] = A; }
                }
            }
            __syncthreads();
        }
    }
    for (int i = t; i < TOPK; i += 1024)
        sel_idx[i] = ~((u32)(sm[i] & 0xFFFFFFFFull));   // recover box index
}

// ---------------- box math helpers (mirror the jax reference) ----------------
__device__ __forceinline__ void box_corners(const float b[7], float cx[8], float cy[8], float cz[8]) {
    const float sx[8] = {0.5f,0.5f,-0.5f,-0.5f,0.5f,0.5f,-0.5f,-0.5f};
    const float sy[8] = {0.5f,-0.5f,-0.5f,0.5f,0.5f,-0.5f,-0.5f,0.5f};
    const float sz[8] = {-0.5f,-0.5f,-0.5f,-0.5f,0.5f,0.5f,0.5f,0.5f};
    float c = __builtin_cosf(b[6]), s = __builtin_sinf(b[6]);
#pragma unroll
    for (int k = 0; k < 8; k++) {
        float x = b[5] * sx[k], y = b[4] * sy[k], z = b[3] * sz[k];
        cx[k] = x * c - y * s + b[0];
        cy[k] = x * s + y * c + b[1];
        cz[k] = z + b[2];
    }
}

__device__ __forceinline__ void proj_T(const float* __restrict__ T, float cx[8], float cy[8], float cz[8]) {
#pragma unroll
    for (int k = 0; k < 8; k++) {
        float x = cx[k], y = cy[k], z = cz[k];
        cx[k] = T[0] * x + T[1] * y + T[2]  * z + T[3];
        cy[k] = T[4] * x + T[5] * y + T[6]  * z + T[7];
        cz[k] = T[8] * x + T[9] * y + T[10] * z + T[11];
    }
}

__device__ __forceinline__ void corner_to_center(const float cx[8], const float cy[8], const float cz[8], float b[7]) {
    float mx = 0.f, my = 0.f, mz = 0.f;
#pragma unroll
    for (int k = 0; k < 8; k++) { mx += cx[k]; my += cy[k]; mz += cz[k]; }
    mx *= 0.125f; my *= 0.125f; mz *= 0.125f;
    float htop = (cz[4] + cz[5] + cz[6] + cz[7]) * 0.25f;
    float hbot = (cz[0] + cz[1] + cz[2] + cz[3]) * 0.25f;
    const int lA[4] = {0,1,4,5}, lB[4] = {3,2,7,6};
    const int wA[4] = {0,3,4,7}, wB[4] = {1,2,5,6};
    float l = 0.f, w = 0.f, dx = 0.f, dy = 0.f;
#pragma unroll
    for (int i = 0; i < 4; i++) {
        float ax = cx[lA[i]] - cx[lB[i]];
        float ay = cy[lA[i]] - cy[lB[i]];
        l += __builtin_sqrtf(ax * ax + ay * ay);
        dx += ax; dy += ay;
    }
#pragma unroll
    for (int i = 0; i < 4; i++) {
        float ax = cx[wA[i]] - cx[wB[i]];
        float ay = cy[wA[i]] - cy[wB[i]];
        w += __builtin_sqrtf(ax * ax + ay * ay);
    }
    b[0] = mx; b[1] = my; b[2] = mz;
    b[3] = htop - hbot;
    b[4] = w * 0.25f;
    b[5] = l * 0.25f;
    b[6] = atan2f(dy, dx);
}

// ---------------- K7: decode selected boxes -> out corners + standup ----------------
__global__ void __launch_bounds__(256) k_boxes(const float* __restrict__ anchors,
                                               const float* __restrict__ psm_v,
                                               const float* __restrict__ psm_i,
                                               const float* __restrict__ rm_v,
                                               const float* __restrict__ rm_i,
                                               const float* __restrict__ tproj,
                                               const float* __restrict__ tego,
                                               const u32* __restrict__ sel_idx,
                                               float* __restrict__ sel_sc,
                                               float* __restrict__ out,
                                               float4* __restrict__ stand) {
    int k = blockIdx.x * blockDim.x + threadIdx.x;
    if (k >= TOPK) return;
    int n = (int)(sel_idx[k] & (u32)(NT - 1));   // defensive mask; identity when valid
    int br = n >> 18;
    int m  = n & (N2 - 1);
    int a  = m & 1;
    int hw = m >> 1;

    // masked score (for NMS valid + final column)
    const float* psm = br ? psm_i : psm_v;
    float xs = psm[a * HW + hw];
    float s  = 1.0f / (1.0f + __builtin_expf(-xs));
    sel_sc[k] = (s > SCORE_THR) ? s : -1.0f;

    // delta -> box
    const float* rm = br ? rm_i : rm_v;
    float d[7];
#pragma unroll
    for (int j = 0; j < 7; j++) d[j] = rm[(a * 7 + j) * HW + hw];
    const float* anc = anchors + (size_t)m * 7;
    float a0 = anc[0], a1 = anc[1], a2 = anc[2], a3 = anc[3], a4 = anc[4], a5 = anc[5], a6 = anc[6];
    float ad = __builtin_sqrtf(a4 * a4 + a5 * a5);
    float b[7];
    b[0] = d[0] * ad + a0;
    b[1] = d[1] * ad + a1;
    b[2] = d[2] * a3 + a2;
    b[3] = __builtin_expf(d[3]) * a3;
    b[4] = __builtin_expf(d[4]) * a4;
    b[5] = __builtin_expf(d[5]) * a5;
    b[6] = d[6] + a6;

    if (br) {  // infrared branch: corners -> t_proj -> back to center form
        float cx[8], cy[8], cz[8];
        box_corners(b, cx, cy, cz);
        proj_T(tproj, cx, cy, cz);
        corner_to_center(cx, cy, cz, b);
    }

    // final corners via t_ego
    float cx[8], cy[8], cz[8];
    box_corners(b, cx, cy, cz);
    proj_T(tego, cx, cy, cz);

    float mnx = cx[0], mny = cy[0], mxx = cx[0], mxy = cy[0];
#pragma unroll
    for (int c = 0; c < 8; c++) {
        out[(size_t)k * 25 + c * 3 + 0] = cx[c];
        out[(size_t)k * 25 + c * 3 + 1] = cy[c];
        out[(size_t)k * 25 + c * 3 + 2] = cz[c];
        mnx = fminf(mnx, cx[c]); mny = fminf(mny, cy[c]);
        mxx = fmaxf(mxx, cx[c]); mxy = fmaxf(mxy, cy[c]);
    }
    stand[k] = make_float4(mnx, mny, mxx, mxy);
}

// ---------------- K8: suppression bitmask (row i x 4096 cols) ----------------
__global__ void __launch_bounds__(64) k_mask(const float4* __restrict__ stand,
                                             u64* __restrict__ mask) {
    int i = blockIdx.x;
    int t = threadIdx.x;
    float4 bi = stand[i];
    float areai = (bi.z - bi.x) * (bi.w - bi.y);
    u64 myword = 0ull;
    for (int w = 0; w < 64; ++w) {
        int j = w * 64 + t;
        float4 bj = stand[j];
        float areaj = (bj.z - bj.x) * (bj.w - bj.y);
        float ltx = fmaxf(bi.x, bj.x), lty = fmaxf(bi.y, bj.y);
        float rbx = fminf(bi.z, bj.z), rby = fminf(bi.w, bj.w);
        float iw = fmaxf(rbx - ltx, 0.0f), ih = fmaxf(rby - lty, 0.0f);
        float inter = iw * ih;
        float iou = inter / (areai + areaj - inter + 1e-6f);
        bool sup = (iou > NMS_THR) && (j > i);
        u64 bits = __ballot(sup);
        if (t == w) myword = bits;
    }
    mask[(size_t)i * 64 + t] = myword;   // coalesced row store
}

// ---------------- K9: sequential greedy NMS (single wave) + final column ----------------
// Serial chain is pure wave-uniform ALU + constant-lane v_readlane; the bulk
// suppression-OR (remv |= kept rows) is decoupled and runs as parallel
// coalesced loads AFTER each chunk's keep-mask is resolved.
__global__ void __launch_bounds__(64) k_nms(const u64* __restrict__ mask,
                                            const float* __restrict__ sc,
                                            float* __restrict__ out) {
    int t = threadIdx.x;
    u64 remv  = 0ull;   // lane t holds global suppression word t
    u64 keepw = 0ull;   // lane t holds keep bits for chunk t
    for (int B = 0; B < 64; ++B) {
        // lane t: row (B*64+t)'s word B = intra-chunk suppression column word
        u64 colB = mask[(size_t)(B * 64 + t) * 64 + B];
        u64 validm = __ballot(sc[B * 64 + t] > SCORE_THR);
        u64 curw = __shfl(remv, B);   // one bpermute pair per chunk only
        u32 clo = (u32)colB, chi = (u32)(colB >> 32);
        u64 kb = 0ull;
#pragma unroll
        for (int r = 0; r < 64; ++r) {
            // constant-lane readlane -> v_readlane_b32 (scalar, hoistable out of chain)
            u64 col_r = ((u64)(u32)__builtin_amdgcn_readlane((int)chi, r) << 32)
                      |  (u64)(u32)__builtin_amdgcn_readlane((int)clo, r);
            u64 k = ((validm >> r) & 1ull) & (~(curw >> r) & 1ull);
            kb   |= k << r;
            curw |= col_r & (0ull - k);   // branchless masked OR
        }
        // fold kept rows into remv: parallel coalesced loads, no serialization
        const u64* rowp = mask + (size_t)(B * 64) * 64 + t;
        for (int r = 0; r < 64; ++r) {
            if ((kb >> r) & 1ull) remv |= rowp[(size_t)r * 64];  // wave-uniform branch
        }
        if (t == B) keepw = kb;
    }
    for (int r = 0; r < 64; ++r) {
        int i = t * 64 + r;
        float s = sc[i];
        out[(size_t)i * 25 + 24] = ((keepw >> r) & 1ull) ? s : 0.0f;
    }
}

extern "C" void kernel_launch(void* const* d_in, const int* in_sizes, int n_in,
                              void* d_out, int out_size, void* d_ws, size_t ws_size,
                              hipStream_t stream) {
    const float* anchors = (const float*)d_in[0];
    const float* psm_v   = (const float*)d_in[1];
    const float* rm_v    = (const float*)d_in[2];
    const float* psm_i   = (const float*)d_in[3];
    const float* rm_i    = (const float*)d_in[4];
    const float* tproj   = (const float*)d_in[5];
    const float* tego    = (const float*)d_in[6];
    float* out = (float*)d_out;
    char* ws = (char*)d_ws;

    u32*    keys    = (u32*)(ws + OFF_KEYS);
    u64*    mask    = (u64*)(ws + OFF_KEYS);    // reuse after keys are consumed
    u64*    cand    = (u64*)(ws + OFF_CAND);
    u32*    hist1   = (u32*)(ws + OFF_HIST1);
    u32*    hist2   = (u32*)(ws + OFF_HIST2);
    u32*    cnt     = (u32*)(ws + OFF_CNT);
    u32*    pivot   = (u32*)(ws + OFF_PIVOT);
    u32*    sel_idx = (u32*)(ws + OFF_SELIDX);
    float*  sel_sc  = (float*)(ws + OFF_SELSC);
    float4* stand   = (float4*)(ws + OFF_STAND);

    // ws is re-poisoned to 0xAA before every launch: zero the accumulators
    hipMemsetAsync(ws + OFF_HIST1, 0, ZERO_BYTES, stream);

    k_keys   <<<NT / 1024, 1024, 0, stream>>>(psm_v, psm_i, keys, hist1);
    k_pivot  <<<1, 1024, 0, stream>>>(hist1, pivot, 0);
    k_hist2  <<<NT / 1024, 1024, 0, stream>>>(keys, pivot, hist2);
    k_pivot  <<<1, 1024, 0, stream>>>(hist2, pivot, 1);
    k_collect<<<NT / 1024, 1024, 0, stream>>>(keys, pivot, cand, cnt);
    k_sort   <<<1, 1024, 0, stream>>>(cand, cnt, sel_idx);
    k_boxes  <<<TOPK / 256, 256, 0, stream>>>(anchors, psm_v, psm_i, rm_v, rm_i,
                                              tproj, tego, sel_idx, sel_sc, out, stand);
    k_mask   <<<TOPK, 64, 0, stream>>>(stand, mask);
    k_nms    <<<1, 64, 0, stream>>>(mask, sel_sc, out);
}

// Round 3
// 495.229 us; speedup vs baseline: 1.9254x; 1.9254x over previous
//
#include <hip/hip_runtime.h>
#include <stdint.h>

typedef unsigned int u32;
typedef unsigned long long u64;

#define HH 256
#define WW 512
#define HW (HH*WW)          // 131072
#define N2 (2*HW)           // 262144 per branch
#define NT (2*N2)           // 524288 total boxes
#define TOPK 4096
#define SCORE_THR 0.2f
#define NMS_THR 0.15f

// ---- workspace layout (bytes) ----
// keys region (2 MB) is reused as the NMS suppression mask (4096*64 u64 = 2 MB)
#define OFF_KEYS   0ull
#define OFF_CAND   ((size_t)NT*4)                 // u64[8192]  @ 2,097,152
#define OFF_HIST1  (OFF_CAND + 8192*8)            // u32[1024]  @ 2,162,688
#define OFF_HIST2  (OFF_HIST1 + 4096)             // u32[1024]
#define OFF_CNT    (OFF_HIST2 + 4096)             // u32 (+pad to 16B)
#define OFF_PIVOT  (OFF_CNT + 16)                 // u32[4]
#define OFF_SELIDX (OFF_PIVOT + 16)               // u32[4096]
#define OFF_SELSC  (OFF_SELIDX + (size_t)TOPK*4)  // f32[4096]
#define OFF_STAND  (OFF_SELSC + (size_t)TOPK*4)   // float4[4096] (16B aligned)
#define ZERO_BYTES (4096 + 4096 + 16)             // hist1+hist2+cnt

// orderable key for float (descending sortable as unsigned)
__device__ __forceinline__ u32 f2ord(float f) {
    u32 b = __float_as_uint(f);
    return (b & 0x80000000u) ? ~b : (b | 0x80000000u);
}

// ---------------- K1: scores -> keys + level-1 histogram ----------------
__global__ void __launch_bounds__(1024) k_keys(const float* __restrict__ psm_v,
                                               const float* __restrict__ psm_i,
                                               u32* __restrict__ keys,
                                               u32* __restrict__ hist1) {
    __shared__ u32 lh[1024];
    int t = threadIdx.x;
    lh[t] = 0;
    __syncthreads();
    int n = blockIdx.x * 1024 + t;
    int br = n >> 18;
    int m  = n & (N2 - 1);
    int a  = m & 1;
    int hw = m >> 1;
    const float* psm = br ? psm_i : psm_v;
    float x = psm[a * HW + hw];
    float s = 1.0f / (1.0f + __builtin_expf(-x));   // mirror ref f32 sigmoid
    u32 key = 0u;                                    // masked (-1.0) entries: key 0, tie->index
    if (s > SCORE_THR) key = f2ord(s);
    keys[n] = key;
    atomicAdd(&lh[key >> 22], 1u);
    __syncthreads();
    u32 c = lh[t];
    if (c) atomicAdd(&hist1[t], c);
}

// ---------------- pivot scan (suffix sums over 1024 bins) ----------------
__global__ void __launch_bounds__(1024) k_pivot(const u32* __restrict__ hist,
                                                u32* __restrict__ pivot, int mode) {
    __shared__ u32 sh[1024];
    int t = threadIdx.x;
    sh[t] = hist[t];
    __syncthreads();
    for (int off = 1; off < 1024; off <<= 1) {
        u32 add = (t + off < 1024) ? sh[t + off] : 0u;
        __syncthreads();
        sh[t] += add;
        __syncthreads();
    }
    u32 target = (mode == 0) ? (u32)TOPK : pivot[2];
    u32 Sb = sh[t];
    u32 Sn = (t < 1023) ? sh[t + 1] : 0u;
    if (Sb >= target && (t == 1023 || Sn < target)) {  // unique writer
        if (mode == 0) {
            pivot[0] = (u32)t;          // level-1 pivot bin
            pivot[2] = target - Sn;     // rank needed inside the bin
        } else {
            pivot[3] = (pivot[0] << 10) | (u32)t;  // 20-bit threshold on key>>12
        }
    }
}

// ---------------- K3: level-2 histogram inside pivot bin ----------------
__global__ void __launch_bounds__(1024) k_hist2(const u32* __restrict__ keys,
                                                const u32* __restrict__ pivot,
                                                u32* __restrict__ hist2) {
    __shared__ u32 lh[1024];
    int t = threadIdx.x;
    lh[t] = 0;
    __syncthreads();
    u32 b1 = pivot[0];
    int n = blockIdx.x * 1024 + t;
    u32 key = keys[n];
    if ((key >> 22) == b1) atomicAdd(&lh[(key >> 12) & 1023u], 1u);
    __syncthreads();
    u32 c = lh[t];
    if (c) atomicAdd(&hist2[t], c);
}

// ---------------- K5: compact candidates >= threshold ----------------
__global__ void __launch_bounds__(1024) k_collect(const u32* __restrict__ keys,
                                                  const u32* __restrict__ pivot,
                                                  u64* __restrict__ cand,
                                                  u32* __restrict__ cnt) {
    int n = blockIdx.x * 1024 + threadIdx.x;
    u32 key = keys[n];
    u32 thr = pivot[3];
    if ((key >> 12) >= thr) {
        u32 pos = atomicAdd(cnt, 1u);
        if (pos < 8192u) cand[pos] = ((u64)key << 32) | (u64)(u32)(~(u32)n);
    }
}

// ---------------- K6: single-block bitonic sort (descending) ----------------
__global__ void __launch_bounds__(1024) k_sort(const u64* __restrict__ cand,
                                               const u32* __restrict__ cnt,
                                               u32* __restrict__ sel_idx) {
    __shared__ u64 sm[8192];   // 64 KB
    int t = threadIdx.x;
    u32 c = *cnt;
    if (c > 8192u) c = 8192u;
    for (int i = t; i < 8192; i += 1024) sm[i] = (i < (int)c) ? cand[i] : 0ull;
    __syncthreads();
    for (int k = 2; k <= 8192; k <<= 1) {
        for (int j = k >> 1; j > 0; j >>= 1) {
            for (int i = t; i < 8192; i += 1024) {
                int l = i ^ j;
                if (l > i) {
                    u64 A = sm[i], B = sm[l];
                    bool desc = ((i & k) == 0);
                    if (desc ? (A < B) : (A > B)) { sm[i] = B; sm[l] = A; }
                }
            }
            __syncthreads();
        }
    }
    for (int i = t; i < TOPK; i += 1024)
        sel_idx[i] = ~((u32)(sm[i] & 0xFFFFFFFFull));   // recover box index
}

// ---------------- box math helpers (mirror the jax reference) ----------------
__device__ __forceinline__ void box_corners(const float b[7], float cx[8], float cy[8], float cz[8]) {
    const float sx[8] = {0.5f,0.5f,-0.5f,-0.5f,0.5f,0.5f,-0.5f,-0.5f};
    const float sy[8] = {0.5f,-0.5f,-0.5f,0.5f,0.5f,-0.5f,-0.5f,0.5f};
    const float sz[8] = {-0.5f,-0.5f,-0.5f,-0.5f,0.5f,0.5f,0.5f,0.5f};
    float c = __builtin_cosf(b[6]), s = __builtin_sinf(b[6]);
#pragma unroll
    for (int k = 0; k < 8; k++) {
        float x = b[5] * sx[k], y = b[4] * sy[k], z = b[3] * sz[k];
        cx[k] = x * c - y * s + b[0];
        cy[k] = x * s + y * c + b[1];
        cz[k] = z + b[2];
    }
}

__device__ __forceinline__ void proj_T(const float* __restrict__ T, float cx[8], float cy[8], float cz[8]) {
#pragma unroll
    for (int k = 0; k < 8; k++) {
        float x = cx[k], y = cy[k], z = cz[k];
        cx[k] = T[0] * x + T[1] * y + T[2]  * z + T[3];
        cy[k] = T[4] * x + T[5] * y + T[6]  * z + T[7];
        cz[k] = T[8] * x + T[9] * y + T[10] * z + T[11];
    }
}

__device__ __forceinline__ void corner_to_center(const float cx[8], const float cy[8], const float cz[8], float b[7]) {
    float mx = 0.f, my = 0.f, mz = 0.f;
#pragma unroll
    for (int k = 0; k < 8; k++) { mx += cx[k]; my += cy[k]; mz += cz[k]; }
    mx *= 0.125f; my *= 0.125f; mz *= 0.125f;
    float htop = (cz[4] + cz[5] + cz[6] + cz[7]) * 0.25f;
    float hbot = (cz[0] + cz[1] + cz[2] + cz[3]) * 0.25f;
    const int lA[4] = {0,1,4,5}, lB[4] = {3,2,7,6};
    const int wA[4] = {0,3,4,7}, wB[4] = {1,2,5,6};
    float l = 0.f, w = 0.f, dx = 0.f, dy = 0.f;
#pragma unroll
    for (int i = 0; i < 4; i++) {
        float ax = cx[lA[i]] - cx[lB[i]];
        float ay = cy[lA[i]] - cy[lB[i]];
        l += __builtin_sqrtf(ax * ax + ay * ay);
        dx += ax; dy += ay;
    }
#pragma unroll
    for (int i = 0; i < 4; i++) {
        float ax = cx[wA[i]] - cx[wB[i]];
        float ay = cy[wA[i]] - cy[wB[i]];
        w += __builtin_sqrtf(ax * ax + ay * ay);
    }
    b[0] = mx; b[1] = my; b[2] = mz;
    b[3] = htop - hbot;
    b[4] = w * 0.25f;
    b[5] = l * 0.25f;
    b[6] = atan2f(dy, dx);
}

// ---------------- K7: decode selected boxes -> out corners + standup ----------------
__global__ void __launch_bounds__(256) k_boxes(const float* __restrict__ anchors,
                                               const float* __restrict__ psm_v,
                                               const float* __restrict__ psm_i,
                                               const float* __restrict__ rm_v,
                                               const float* __restrict__ rm_i,
                                               const float* __restrict__ tproj,
                                               const float* __restrict__ tego,
                                               const u32* __restrict__ sel_idx,
                                               float* __restrict__ sel_sc,
                                               float* __restrict__ out,
                                               float4* __restrict__ stand) {
    int k = blockIdx.x * blockDim.x + threadIdx.x;
    if (k >= TOPK) return;
    int n = (int)(sel_idx[k] & (u32)(NT - 1));   // defensive mask; identity when valid
    int br = n >> 18;
    int m  = n & (N2 - 1);
    int a  = m & 1;
    int hw = m >> 1;

    // masked score (for NMS valid + final column)
    const float* psm = br ? psm_i : psm_v;
    float xs = psm[a * HW + hw];
    float s  = 1.0f / (1.0f + __builtin_expf(-xs));
    sel_sc[k] = (s > SCORE_THR) ? s : -1.0f;

    // delta -> box
    const float* rm = br ? rm_i : rm_v;
    float d[7];
#pragma unroll
    for (int j = 0; j < 7; j++) d[j] = rm[(a * 7 + j) * HW + hw];
    const float* anc = anchors + (size_t)m * 7;
    float a0 = anc[0], a1 = anc[1], a2 = anc[2], a3 = anc[3], a4 = anc[4], a5 = anc[5], a6 = anc[6];
    float ad = __builtin_sqrtf(a4 * a4 + a5 * a5);
    float b[7];
    b[0] = d[0] * ad + a0;
    b[1] = d[1] * ad + a1;
    b[2] = d[2] * a3 + a2;
    b[3] = __builtin_expf(d[3]) * a3;
    b[4] = __builtin_expf(d[4]) * a4;
    b[5] = __builtin_expf(d[5]) * a5;
    b[6] = d[6] + a6;

    if (br) {  // infrared branch: corners -> t_proj -> back to center form
        float cx[8], cy[8], cz[8];
        box_corners(b, cx, cy, cz);
        proj_T(tproj, cx, cy, cz);
        corner_to_center(cx, cy, cz, b);
    }

    // final corners via t_ego
    float cx[8], cy[8], cz[8];
    box_corners(b, cx, cy, cz);
    proj_T(tego, cx, cy, cz);

    float mnx = cx[0], mny = cy[0], mxx = cx[0], mxy = cy[0];
#pragma unroll
    for (int c = 0; c < 8; c++) {
        out[(size_t)k * 25 + c * 3 + 0] = cx[c];
        out[(size_t)k * 25 + c * 3 + 1] = cy[c];
        out[(size_t)k * 25 + c * 3 + 2] = cz[c];
        mnx = fminf(mnx, cx[c]); mny = fminf(mny, cy[c]);
        mxx = fmaxf(mxx, cx[c]); mxy = fmaxf(mxy, cy[c]);
    }
    stand[k] = make_float4(mnx, mny, mxx, mxy);
}

// ---------------- K8: suppression bitmask (row i x 4096 cols) ----------------
__global__ void __launch_bounds__(64) k_mask(const float4* __restrict__ stand,
                                             u64* __restrict__ mask) {
    int i = blockIdx.x;
    int t = threadIdx.x;
    float4 bi = stand[i];
    float areai = (bi.z - bi.x) * (bi.w - bi.y);
    u64 myword = 0ull;
    for (int w = 0; w < 64; ++w) {
        int j = w * 64 + t;
        float4 bj = stand[j];
        float areaj = (bj.z - bj.x) * (bj.w - bj.y);
        float ltx = fmaxf(bi.x, bj.x), lty = fmaxf(bi.y, bj.y);
        float rbx = fminf(bi.z, bj.z), rby = fminf(bi.w, bj.w);
        float iw = fmaxf(rbx - ltx, 0.0f), ih = fmaxf(rby - lty, 0.0f);
        float inter = iw * ih;
        float iou = inter / (areai + areaj - inter + 1e-6f);
        bool sup = (iou > NMS_THR) && (j > i);
        u64 bits = __ballot(sup);
        if (t == w) myword = bits;
    }
    mask[(size_t)i * 64 + t] = myword;   // coalesced row store
}

// ---------------- K9: sequential greedy NMS (single wave) + final column ----------------
// All load addresses are chain-independent: 64 row-words prefetched into
// registers per chunk (coalesced, in-flight during the chain), fold is
// branchless masked-OR. The serial chain itself is wave-uniform scalar ALU
// fed by constant-lane v_readlane broadcasts of the in-register colB.
__global__ void __launch_bounds__(64) k_nms(const u64* __restrict__ mask,
                                            const float* __restrict__ sc,
                                            float* __restrict__ out) {
    int t = threadIdx.x;
    u64 remv  = 0ull;   // lane t holds global suppression word t
    u64 keepw = 0ull;   // lane t holds keep bits for chunk t
    // preload chunk 0's intra-chunk column word: lane t = mask[(0*64+t)*64 + 0]
    u64 colB = mask[(size_t)t * 64];
    for (int B = 0; B < 64; ++B) {
        // prefetch all 64 row-words of this chunk (coalesced, chain-independent)
        const u64* rowp = mask + (size_t)(B * 64) * 64 + t;
        u64 rw[64];
#pragma unroll
        for (int r = 0; r < 64; ++r) rw[r] = rowp[(size_t)r * 64];
        // prefetch next chunk's colB while this chunk resolves
        u64 colB_next = (B < 63) ? mask[(size_t)((B + 1) * 64 + t) * 64 + (B + 1)] : 0ull;
        u64 validm = __ballot(sc[B * 64 + t] > SCORE_THR);
        // broadcast remv word B -> wave-uniform scalar
        u64 curw = ((u64)(u32)__builtin_amdgcn_readlane((int)(u32)(remv >> 32), B) << 32)
                 |  (u64)(u32)__builtin_amdgcn_readlane((int)(u32)remv, B);
        u32 clo = (u32)colB, chi = (u32)(colB >> 32);
        u64 kb = 0ull;
#pragma unroll
        for (int r = 0; r < 64; ++r) {
            // constant lane -> v_readlane_b32; value feeds scalar chain
            u64 col_r = ((u64)(u32)__builtin_amdgcn_readlane((int)chi, r) << 32)
                      |  (u64)(u32)__builtin_amdgcn_readlane((int)clo, r);
            u64 k = ((validm >> r) & 1ull) & (~(curw >> r) & 1ull);
            kb   |= k << r;
            curw |= col_r & (0ull - k);   // branchless masked OR
        }
        // branchless fold: OR kept rows into remv (data already in registers)
#pragma unroll
        for (int r = 0; r < 64; ++r)
            remv |= rw[r] & (0ull - ((kb >> r) & 1ull));
        if (t == B) keepw = kb;
        colB = colB_next;
    }
    for (int r = 0; r < 64; ++r) {
        int i = t * 64 + r;
        float s = sc[i];
        out[(size_t)i * 25 + 24] = ((keepw >> r) & 1ull) ? s : 0.0f;
    }
}

extern "C" void kernel_launch(void* const* d_in, const int* in_sizes, int n_in,
                              void* d_out, int out_size, void* d_ws, size_t ws_size,
                              hipStream_t stream) {
    const float* anchors = (const float*)d_in[0];
    const float* psm_v   = (const float*)d_in[1];
    const float* rm_v    = (const float*)d_in[2];
    const float* psm_i   = (const float*)d_in[3];
    const float* rm_i    = (const float*)d_in[4];
    const float* tproj   = (const float*)d_in[5];
    const float* tego    = (const float*)d_in[6];
    float* out = (float*)d_out;
    char* ws = (char*)d_ws;

    u32*    keys    = (u32*)(ws + OFF_KEYS);
    u64*    mask    = (u64*)(ws + OFF_KEYS);    // reuse after keys are consumed
    u64*    cand    = (u64*)(ws + OFF_CAND);
    u32*    hist1   = (u32*)(ws + OFF_HIST1);
    u32*    hist2   = (u32*)(ws + OFF_HIST2);
    u32*    cnt     = (u32*)(ws + OFF_CNT);
    u32*    pivot   = (u32*)(ws + OFF_PIVOT);
    u32*    sel_idx = (u32*)(ws + OFF_SELIDX);
    float*  sel_sc  = (float*)(ws + OFF_SELSC);
    float4* stand   = (float4*)(ws + OFF_STAND);

    // ws is re-poisoned to 0xAA before every launch: zero the accumulators
    hipMemsetAsync(ws + OFF_HIST1, 0, ZERO_BYTES, stream);

    k_keys   <<<NT / 1024, 1024, 0, stream>>>(psm_v, psm_i, keys, hist1);
    k_pivot  <<<1, 1024, 0, stream>>>(hist1, pivot, 0);
    k_hist2  <<<NT / 1024, 1024, 0, stream>>>(keys, pivot, hist2);
    k_pivot  <<<1, 1024, 0, stream>>>(hist2, pivot, 1);
    k_collect<<<NT / 1024, 1024, 0, stream>>>(keys, pivot, cand, cnt);
    k_sort   <<<1, 1024, 0, stream>>>(cand, cnt, sel_idx);
    k_boxes  <<<TOPK / 256, 256, 0, stream>>>(anchors, psm_v, psm_i, rm_v, rm_i,
                                              tproj, tego, sel_idx, sel_sc, out, stand);
    k_mask   <<<TOPK, 64, 0, stream>>>(stand, mask);
    k_nms    <<<1, 64, 0, stream>>>(mask, sel_sc, out);
}

// Round 4
// 466.708 us; speedup vs baseline: 2.0431x; 1.0611x over previous
//
#include <hip/hip_runtime.h>
#include <stdint.h>

typedef unsigned int u32;
typedef unsigned long long u64;

#define HH 256
#define WW 512
#define HW (HH*WW)          // 131072
#define N2 (2*HW)           // 262144 per branch
#define NT (2*N2)           // 524288 total boxes
#define TOPK 4096
#define SCORE_THR 0.2f
#define NMS_THR 0.15f

// ---- workspace layout (bytes) ----
// keys region (2 MB) is reused as the NMS suppression mask (4096*64 u64 = 2 MB)
#define OFF_KEYS   0ull
#define OFF_CAND   ((size_t)NT*4)                 // u64[8192]  @ 2,097,152
#define OFF_HIST1  (OFF_CAND + 8192*8)            // u32[1024]  @ 2,162,688
#define OFF_HIST2  (OFF_HIST1 + 4096)             // u32[1024]
#define OFF_CNT    (OFF_HIST2 + 4096)             // u32 (+pad to 16B)
#define OFF_PIVOT  (OFF_CNT + 16)                 // u32[4]
#define OFF_SELIDX (OFF_PIVOT + 16)               // u32[4096]
#define OFF_SELSC  (OFF_SELIDX + (size_t)TOPK*4)  // f32[4096]
#define OFF_STAND  (OFF_SELSC + (size_t)TOPK*4)   // float4[4096] (16B aligned)
#define ZERO_BYTES (4096 + 4096 + 16)             // hist1+hist2+cnt

// orderable key for float (descending sortable as unsigned)
__device__ __forceinline__ u32 f2ord(float f) {
    u32 b = __float_as_uint(f);
    return (b & 0x80000000u) ? ~b : (b | 0x80000000u);
}

// ---------------- K1: scores -> keys + level-1 histogram ----------------
__global__ void __launch_bounds__(1024) k_keys(const float* __restrict__ psm_v,
                                               const float* __restrict__ psm_i,
                                               u32* __restrict__ keys,
                                               u32* __restrict__ hist1) {
    __shared__ u32 lh[1024];
    int t = threadIdx.x;
    lh[t] = 0;
    __syncthreads();
    int n = blockIdx.x * 1024 + t;
    int br = n >> 18;
    int m  = n & (N2 - 1);
    int a  = m & 1;
    int hw = m >> 1;
    const float* psm = br ? psm_i : psm_v;
    float x = psm[a * HW + hw];
    float s = 1.0f / (1.0f + __builtin_expf(-x));   // mirror ref f32 sigmoid
    u32 key = 0u;                                    // masked (-1.0) entries: key 0, tie->index
    if (s > SCORE_THR) key = f2ord(s);
    keys[n] = key;
    atomicAdd(&lh[key >> 22], 1u);
    __syncthreads();
    u32 c = lh[t];
    if (c) atomicAdd(&hist1[t], c);
}

// ---------------- pivot scan (suffix sums over 1024 bins) ----------------
__global__ void __launch_bounds__(1024) k_pivot(const u32* __restrict__ hist,
                                                u32* __restrict__ pivot, int mode) {
    __shared__ u32 sh[1024];
    int t = threadIdx.x;
    sh[t] = hist[t];
    __syncthreads();
    for (int off = 1; off < 1024; off <<= 1) {
        u32 add = (t + off < 1024) ? sh[t + off] : 0u;
        __syncthreads();
        sh[t] += add;
        __syncthreads();
    }
    u32 target = (mode == 0) ? (u32)TOPK : pivot[2];
    u32 Sb = sh[t];
    u32 Sn = (t < 1023) ? sh[t + 1] : 0u;
    if (Sb >= target && (t == 1023 || Sn < target)) {  // unique writer
        if (mode == 0) {
            pivot[0] = (u32)t;          // level-1 pivot bin
            pivot[2] = target - Sn;     // rank needed inside the bin
        } else {
            pivot[3] = (pivot[0] << 10) | (u32)t;  // 20-bit threshold on key>>12
        }
    }
}

// ---------------- K3: level-2 histogram inside pivot bin ----------------
__global__ void __launch_bounds__(1024) k_hist2(const u32* __restrict__ keys,
                                                const u32* __restrict__ pivot,
                                                u32* __restrict__ hist2) {
    __shared__ u32 lh[1024];
    int t = threadIdx.x;
    lh[t] = 0;
    __syncthreads();
    u32 b1 = pivot[0];
    int n = blockIdx.x * 1024 + t;
    u32 key = keys[n];
    if ((key >> 22) == b1) atomicAdd(&lh[(key >> 12) & 1023u], 1u);
    __syncthreads();
    u32 c = lh[t];
    if (c) atomicAdd(&hist2[t], c);
}

// ---------------- K5: compact candidates >= threshold ----------------
__global__ void __launch_bounds__(1024) k_collect(const u32* __restrict__ keys,
                                                  const u32* __restrict__ pivot,
                                                  u64* __restrict__ cand,
                                                  u32* __restrict__ cnt) {
    int n = blockIdx.x * 1024 + threadIdx.x;
    u32 key = keys[n];
    u32 thr = pivot[3];
    if ((key >> 12) >= thr) {
        u32 pos = atomicAdd(cnt, 1u);
        if (pos < 8192u) cand[pos] = ((u64)key << 32) | (u64)(u32)(~(u32)n);
    }
}

// ---------------- K6: single-block bitonic sort (descending) ----------------
__global__ void __launch_bounds__(1024) k_sort(const u64* __restrict__ cand,
                                               const u32* __restrict__ cnt,
                                               u32* __restrict__ sel_idx) {
    __shared__ u64 sm[8192];   // 64 KB
    int t = threadIdx.x;
    u32 c = *cnt;
    if (c > 8192u) c = 8192u;
    for (int i = t; i < 8192; i += 1024) sm[i] = (i < (int)c) ? cand[i] : 0ull;
    __syncthreads();
    for (int k = 2; k <= 8192; k <<= 1) {
        for (int j = k >> 1; j > 0; j >>= 1) {
            for (int i = t; i < 8192; i += 1024) {
                int l = i ^ j;
                if (l > i) {
                    u64 A = sm[i], B = sm[l];
                    bool desc = ((i & k) == 0);
                    if (desc ? (A < B) : (A > B)) { sm[i] = B; sm[l] = A; }
                }
            }
            __syncthreads();
        }
    }
    for (int i = t; i < TOPK; i += 1024)
        sel_idx[i] = ~((u32)(sm[i] & 0xFFFFFFFFull));   // recover box index
}

// ---------------- box math helpers (mirror the jax reference) ----------------
__device__ __forceinline__ void box_corners(const float b[7], float cx[8], float cy[8], float cz[8]) {
    const float sx[8] = {0.5f,0.5f,-0.5f,-0.5f,0.5f,0.5f,-0.5f,-0.5f};
    const float sy[8] = {0.5f,-0.5f,-0.5f,0.5f,0.5f,-0.5f,-0.5f,0.5f};
    const float sz[8] = {-0.5f,-0.5f,-0.5f,-0.5f,0.5f,0.5f,0.5f,0.5f};
    float c = __builtin_cosf(b[6]), s = __builtin_sinf(b[6]);
#pragma unroll
    for (int k = 0; k < 8; k++) {
        float x = b[5] * sx[k], y = b[4] * sy[k], z = b[3] * sz[k];
        cx[k] = x * c - y * s + b[0];
        cy[k] = x * s + y * c + b[1];
        cz[k] = z + b[2];
    }
}

__device__ __forceinline__ void proj_T(const float* __restrict__ T, float cx[8], float cy[8], float cz[8]) {
#pragma unroll
    for (int k = 0; k < 8; k++) {
        float x = cx[k], y = cy[k], z = cz[k];
        cx[k] = T[0] * x + T[1] * y + T[2]  * z + T[3];
        cy[k] = T[4] * x + T[5] * y + T[6]  * z + T[7];
        cz[k] = T[8] * x + T[9] * y + T[10] * z + T[11];
    }
}

__device__ __forceinline__ void corner_to_center(const float cx[8], const float cy[8], const float cz[8], float b[7]) {
    float mx = 0.f, my = 0.f, mz = 0.f;
#pragma unroll
    for (int k = 0; k < 8; k++) { mx += cx[k]; my += cy[k]; mz += cz[k]; }
    mx *= 0.125f; my *= 0.125f; mz *= 0.125f;
    float htop = (cz[4] + cz[5] + cz[6] + cz[7]) * 0.25f;
    float hbot = (cz[0] + cz[1] + cz[2] + cz[3]) * 0.25f;
    const int lA[4] = {0,1,4,5}, lB[4] = {3,2,7,6};
    const int wA[4] = {0,3,4,7}, wB[4] = {1,2,5,6};
    float l = 0.f, w = 0.f, dx = 0.f, dy = 0.f;
#pragma unroll
    for (int i = 0; i < 4; i++) {
        float ax = cx[lA[i]] - cx[lB[i]];
        float ay = cy[lA[i]] - cy[lB[i]];
        l += __builtin_sqrtf(ax * ax + ay * ay);
        dx += ax; dy += ay;
    }
#pragma unroll
    for (int i = 0; i < 4; i++) {
        float ax = cx[wA[i]] - cx[wB[i]];
        float ay = cy[wA[i]] - cy[wB[i]];
        w += __builtin_sqrtf(ax * ax + ay * ay);
    }
    b[0] = mx; b[1] = my; b[2] = mz;
    b[3] = htop - hbot;
    b[4] = w * 0.25f;
    b[5] = l * 0.25f;
    b[6] = atan2f(dy, dx);
}

// ---------------- K7: decode selected boxes -> out corners + standup ----------------
__global__ void __launch_bounds__(256) k_boxes(const float* __restrict__ anchors,
                                               const float* __restrict__ psm_v,
                                               const float* __restrict__ psm_i,
                                               const float* __restrict__ rm_v,
                                               const float* __restrict__ rm_i,
                                               const float* __restrict__ tproj,
                                               const float* __restrict__ tego,
                                               const u32* __restrict__ sel_idx,
                                               float* __restrict__ sel_sc,
                                               float* __restrict__ out,
                                               float4* __restrict__ stand) {
    int k = blockIdx.x * blockDim.x + threadIdx.x;
    if (k >= TOPK) return;
    int n = (int)(sel_idx[k] & (u32)(NT - 1));   // defensive mask; identity when valid
    int br = n >> 18;
    int m  = n & (N2 - 1);
    int a  = m & 1;
    int hw = m >> 1;

    // masked score (for NMS valid + final column)
    const float* psm = br ? psm_i : psm_v;
    float xs = psm[a * HW + hw];
    float s  = 1.0f / (1.0f + __builtin_expf(-xs));
    sel_sc[k] = (s > SCORE_THR) ? s : -1.0f;

    // delta -> box
    const float* rm = br ? rm_i : rm_v;
    float d[7];
#pragma unroll
    for (int j = 0; j < 7; j++) d[j] = rm[(a * 7 + j) * HW + hw];
    const float* anc = anchors + (size_t)m * 7;
    float a0 = anc[0], a1 = anc[1], a2 = anc[2], a3 = anc[3], a4 = anc[4], a5 = anc[5], a6 = anc[6];
    float ad = __builtin_sqrtf(a4 * a4 + a5 * a5);
    float b[7];
    b[0] = d[0] * ad + a0;
    b[1] = d[1] * ad + a1;
    b[2] = d[2] * a3 + a2;
    b[3] = __builtin_expf(d[3]) * a3;
    b[4] = __builtin_expf(d[4]) * a4;
    b[5] = __builtin_expf(d[5]) * a5;
    b[6] = d[6] + a6;

    if (br) {  // infrared branch: corners -> t_proj -> back to center form
        float cx[8], cy[8], cz[8];
        box_corners(b, cx, cy, cz);
        proj_T(tproj, cx, cy, cz);
        corner_to_center(cx, cy, cz, b);
    }

    // final corners via t_ego
    float cx[8], cy[8], cz[8];
    box_corners(b, cx, cy, cz);
    proj_T(tego, cx, cy, cz);

    float mnx = cx[0], mny = cy[0], mxx = cx[0], mxy = cy[0];
#pragma unroll
    for (int c = 0; c < 8; c++) {
        out[(size_t)k * 25 + c * 3 + 0] = cx[c];
        out[(size_t)k * 25 + c * 3 + 1] = cy[c];
        out[(size_t)k * 25 + c * 3 + 2] = cz[c];
        mnx = fminf(mnx, cx[c]); mny = fminf(mny, cy[c]);
        mxx = fmaxf(mxx, cx[c]); mxy = fmaxf(mxy, cy[c]);
    }
    stand[k] = make_float4(mnx, mny, mxx, mxy);
}

// ---------------- K8: suppression bitmask (row i x 4096 cols) ----------------
__global__ void __launch_bounds__(64) k_mask(const float4* __restrict__ stand,
                                             u64* __restrict__ mask) {
    int i = blockIdx.x;
    int t = threadIdx.x;
    float4 bi = stand[i];
    float areai = (bi.z - bi.x) * (bi.w - bi.y);
    u64 myword = 0ull;
    for (int w = 0; w < 64; ++w) {
        int j = w * 64 + t;
        float4 bj = stand[j];
        float areaj = (bj.z - bj.x) * (bj.w - bj.y);
        float ltx = fmaxf(bi.x, bj.x), lty = fmaxf(bi.y, bj.y);
        float rbx = fminf(bi.z, bj.z), rby = fminf(bi.w, bj.w);
        float iw = fmaxf(rbx - ltx, 0.0f), ih = fmaxf(rby - lty, 0.0f);
        float inter = iw * ih;
        float iou = inter / (areai + areaj - inter + 1e-6f);
        bool sup = (iou > NMS_THR) && (j > i);
        u64 bits = __ballot(sup);
        if (t == w) myword = bits;
    }
    mask[(size_t)i * 64 + t] = myword;   // coalesced row store
}

// ---------------- K9: block-cooperative sequential greedy NMS ----------------
// Wave 0 resolves the serial keep chain (scalar ALU + readlane, using only the
// intra-chunk column words + remv_sh[B]); all 16 waves cooperatively prefetch
// the chunk's 64x64 row-words (4/thread, issued before the barrier so they fly
// during the chain) and fold kept rows into LDS remv_sh via atomicOr.
__global__ void __launch_bounds__(1024) k_nms(const u64* __restrict__ mask,
                                              const float* __restrict__ sc,
                                              float* __restrict__ out) {
    __shared__ u64 remv_sh[64];
    __shared__ u64 keep_sh[64];
    __shared__ u64 kb_sh;
    int tid = threadIdx.x;
    int w = tid >> 6, l = tid & 63;
    if (tid < 64) remv_sh[tid] = 0ull;
    __syncthreads();
    u64 colB = 0ull;
    float mysc = 0.0f;
    if (w == 0) { colB = mask[(size_t)l * 64]; mysc = sc[l]; }
    for (int B = 0; B < 64; ++B) {
        // all threads: issue this chunk's row loads (chain-independent, coalesced)
        const u64* rowp = mask + ((size_t)(B * 64 + w * 4) * 64) + l;
        u64 rw0 = rowp[0];
        u64 rw1 = rowp[64];
        u64 rw2 = rowp[128];
        u64 rw3 = rowp[192];
        u64 colB_next = 0ull;
        float sc_next = 0.0f;
        if (w == 0) {
            if (B < 63) {   // prefetch next chunk's column word + scores
                colB_next = mask[(size_t)((B + 1) * 64 + l) * 64 + (B + 1)];
                sc_next   = sc[(B + 1) * 64 + l];
            }
            u64 validm = __ballot(mysc > SCORE_THR);
            u64 curw = remv_sh[B];          // folds of chunks < B (barrier-ordered)
            u32 clo = (u32)colB, chi = (u32)(colB >> 32);
            u64 kb = 0ull;
#pragma unroll
            for (int r = 0; r < 64; ++r) {
                u64 col_r = ((u64)(u32)__builtin_amdgcn_readlane((int)chi, r) << 32)
                          |  (u64)(u32)__builtin_amdgcn_readlane((int)clo, r);
                u64 k = ((validm >> r) & 1ull) & (~(curw >> r) & 1ull);
                kb   |= k << r;
                curw |= col_r & (0ull - k);  // branchless masked OR
            }
            if (l == 0) { kb_sh = kb; keep_sh[B] = kb; }
        }
        __syncthreads();     // kb_sh visible; remv_sh[B] read precedes fold writes
        u64 kb = kb_sh;
        int rbase = w * 4;
        u64 p = (rw0 & (0ull - ((kb >> (rbase + 0)) & 1ull)))
              | (rw1 & (0ull - ((kb >> (rbase + 1)) & 1ull)))
              | (rw2 & (0ull - ((kb >> (rbase + 2)) & 1ull)))
              | (rw3 & (0ull - ((kb >> (rbase + 3)) & 1ull)));
        if (p) atomicOr(&remv_sh[l], p);
        __syncthreads();     // fold(B) complete before chain reads remv_sh[B+1]
        colB = colB_next;
        mysc = sc_next;
    }
    // final score column (keep_sh complete after last barrier)
#pragma unroll
    for (int j = 0; j < 4; ++j) {
        int i = tid * 4 + j;
        float s = sc[i];
        out[(size_t)i * 25 + 24] = ((keep_sh[i >> 6] >> (i & 63)) & 1ull) ? s : 0.0f;
    }
}

extern "C" void kernel_launch(void* const* d_in, const int* in_sizes, int n_in,
                              void* d_out, int out_size, void* d_ws, size_t ws_size,
                              hipStream_t stream) {
    const float* anchors = (const float*)d_in[0];
    const float* psm_v   = (const float*)d_in[1];
    const float* rm_v    = (const float*)d_in[2];
    const float* psm_i   = (const float*)d_in[3];
    const float* rm_i    = (const float*)d_in[4];
    const float* tproj   = (const float*)d_in[5];
    const float* tego    = (const float*)d_in[6];
    float* out = (float*)d_out;
    char* ws = (char*)d_ws;

    u32*    keys    = (u32*)(ws + OFF_KEYS);
    u64*    mask    = (u64*)(ws + OFF_KEYS);    // reuse after keys are consumed
    u64*    cand    = (u64*)(ws + OFF_CAND);
    u32*    hist1   = (u32*)(ws + OFF_HIST1);
    u32*    hist2   = (u32*)(ws + OFF_HIST2);
    u32*    cnt     = (u32*)(ws + OFF_CNT);
    u32*    pivot   = (u32*)(ws + OFF_PIVOT);
    u32*    sel_idx = (u32*)(ws + OFF_SELIDX);
    float*  sel_sc  = (float*)(ws + OFF_SELSC);
    float4* stand   = (float4*)(ws + OFF_STAND);

    // ws is re-poisoned to 0xAA before every launch: zero the accumulators
    hipMemsetAsync(ws + OFF_HIST1, 0, ZERO_BYTES, stream);

    k_keys   <<<NT / 1024, 1024, 0, stream>>>(psm_v, psm_i, keys, hist1);
    k_pivot  <<<1, 1024, 0, stream>>>(hist1, pivot, 0);
    k_hist2  <<<NT / 1024, 1024, 0, stream>>>(keys, pivot, hist2);
    k_pivot  <<<1, 1024, 0, stream>>>(hist2, pivot, 1);
    k_collect<<<NT / 1024, 1024, 0, stream>>>(keys, pivot, cand, cnt);
    k_sort   <<<1, 1024, 0, stream>>>(cand, cnt, sel_idx);
    k_boxes  <<<TOPK / 256, 256, 0, stream>>>(anchors, psm_v, psm_i, rm_v, rm_i,
                                              tproj, tego, sel_idx, sel_sc, out, stand);
    k_mask   <<<TOPK, 64, 0, stream>>>(stand, mask);
    k_nms    <<<1, 1024, 0, stream>>>(mask, sel_sc, out);
}

// Round 6
// 356.347 us; speedup vs baseline: 2.6758x; 1.3097x over previous
//
#include <hip/hip_runtime.h>
#include <stdint.h>

typedef unsigned int u32;
typedef unsigned long long u64;

#define HH 256
#define WW 512
#define HW (HH*WW)          // 131072
#define N2 (2*HW)           // 262144 per branch
#define NT (2*N2)           // 524288 total boxes
#define TOPK 4096
#define SCORE_THR 0.2f
#define NMS_THR 0.15f

// ---- workspace layout (bytes) ----
// keys region (2 MB) is reused as the NMS suppression mask (4096*64 u64 = 2 MB)
#define OFF_KEYS   0ull
#define OFF_CAND   ((size_t)NT*4)                 // u64[8192]  @ 2,097,152
#define OFF_HIST1  (OFF_CAND + 8192*8)            // u32[1024]  @ 2,162,688
#define OFF_HIST2  (OFF_HIST1 + 4096)             // u32[1024]
#define OFF_CNT    (OFF_HIST2 + 4096)             // u32 (+pad to 16B)
#define OFF_PIVOT  (OFF_CNT + 16)                 // u32[4]
#define OFF_SELIDX (OFF_PIVOT + 16)               // u32[4096]
#define OFF_SELSC  (OFF_SELIDX + (size_t)TOPK*4)  // f32[4096]
#define OFF_STAND  (OFF_SELSC + (size_t)TOPK*4)   // float4[4096] (16B aligned)
#define ZERO_BYTES (4096 + 4096 + 16)             // hist1+hist2+cnt

// orderable key for float (descending sortable as unsigned)
__device__ __forceinline__ u32 f2ord(float f) {
    u32 b = __float_as_uint(f);
    return (b & 0x80000000u) ? ~b : (b | 0x80000000u);
}

// ---------------- K1: scores -> keys + level-1 histogram ----------------
__global__ void __launch_bounds__(1024) k_keys(const float* __restrict__ psm_v,
                                               const float* __restrict__ psm_i,
                                               u32* __restrict__ keys,
                                               u32* __restrict__ hist1) {
    __shared__ u32 lh[1024];
    int t = threadIdx.x;
    lh[t] = 0;
    __syncthreads();
    int n = blockIdx.x * 1024 + t;
    int br = n >> 18;
    int m  = n & (N2 - 1);
    int a  = m & 1;
    int hw = m >> 1;
    const float* psm = br ? psm_i : psm_v;
    float x = psm[a * HW + hw];
    float s = 1.0f / (1.0f + __builtin_expf(-x));   // mirror ref f32 sigmoid
    u32 key = 0u;                                    // masked (-1.0) entries: key 0, tie->index
    if (s > SCORE_THR) key = f2ord(s);
    keys[n] = key;
    atomicAdd(&lh[key >> 22], 1u);
    __syncthreads();
    u32 c = lh[t];
    if (c) atomicAdd(&hist1[t], c);
}

// ---------------- pivot scan (suffix sums over 1024 bins) ----------------
__global__ void __launch_bounds__(1024) k_pivot(const u32* __restrict__ hist,
                                                u32* __restrict__ pivot, int mode) {
    __shared__ u32 sh[1024];
    int t = threadIdx.x;
    sh[t] = hist[t];
    __syncthreads();
    for (int off = 1; off < 1024; off <<= 1) {
        u32 add = (t + off < 1024) ? sh[t + off] : 0u;
        __syncthreads();
        sh[t] += add;
        __syncthreads();
    }
    u32 target = (mode == 0) ? (u32)TOPK : pivot[2];
    u32 Sb = sh[t];
    u32 Sn = (t < 1023) ? sh[t + 1] : 0u;
    if (Sb >= target && (t == 1023 || Sn < target)) {  // unique writer
        if (mode == 0) {
            pivot[0] = (u32)t;          // level-1 pivot bin
            pivot[2] = target - Sn;     // rank needed inside the bin
        } else {
            pivot[3] = (pivot[0] << 10) | (u32)t;  // 20-bit threshold on key>>12
        }
    }
}

// ---------------- K3: level-2 histogram inside pivot bin ----------------
__global__ void __launch_bounds__(1024) k_hist2(const u32* __restrict__ keys,
                                                const u32* __restrict__ pivot,
                                                u32* __restrict__ hist2) {
    __shared__ u32 lh[1024];
    int t = threadIdx.x;
    lh[t] = 0;
    __syncthreads();
    u32 b1 = pivot[0];
    int n = blockIdx.x * 1024 + t;
    u32 key = keys[n];
    if ((key >> 22) == b1) atomicAdd(&lh[(key >> 12) & 1023u], 1u);
    __syncthreads();
    u32 c = lh[t];
    if (c) atomicAdd(&hist2[t], c);
}

// ---------------- K5: compact candidates >= threshold ----------------
__global__ void __launch_bounds__(1024) k_collect(const u32* __restrict__ keys,
                                                  const u32* __restrict__ pivot,
                                                  u64* __restrict__ cand,
                                                  u32* __restrict__ cnt) {
    int n = blockIdx.x * 1024 + threadIdx.x;
    u32 key = keys[n];
    u32 thr = pivot[3];
    if ((key >> 12) >= thr) {
        u32 pos = atomicAdd(cnt, 1u);
        if (pos < 8192u) cand[pos] = ((u64)key << 32) | (u64)(u32)(~(u32)n);
    }
}

// ---------------- K6: rank-by-counting selection (replaces bitonic sort) ----
// Keys are distinct (index embedded), so rank = #{keys > mine} is an exact
// permutation; rank < TOPK keeps exactly the reference's descending order.
__global__ void __launch_bounds__(256) k_rank(const u64* __restrict__ cand,
                                              const u32* __restrict__ cnt,
                                              u32* __restrict__ sel_idx) {
    __shared__ u64 tile[1024];
    int tid = threadIdx.x;
    int i = blockIdx.x * 256 + tid;
    u32 c = *cnt;
    if (c > 8192u) c = 8192u;
    u64 my = (i < (int)c) ? cand[i] : 0ull;
    u32 rank = 0;
    for (u32 base = 0; base < c; base += 1024) {
#pragma unroll
        for (int k = 0; k < 4; ++k) {
            u32 idx = base + tid + k * 256;
            tile[tid + k * 256] = (idx < c) ? cand[idx] : 0ull;
        }
        __syncthreads();
        u32 lim = (c - base < 1024u) ? (c - base) : 1024u;
#pragma unroll 4
        for (u32 k = 0; k < lim; ++k) rank += (tile[k] > my) ? 1u : 0u;
        __syncthreads();
    }
    if (i < (int)c && rank < (u32)TOPK)
        sel_idx[rank] = ~((u32)(my & 0xFFFFFFFFull));
}

// ---------------- box math helpers (mirror the jax reference) ----------------
__device__ __forceinline__ void box_corners(const float b[7], float cx[8], float cy[8], float cz[8]) {
    const float sx[8] = {0.5f,0.5f,-0.5f,-0.5f,0.5f,0.5f,-0.5f,-0.5f};
    const float sy[8] = {0.5f,-0.5f,-0.5f,0.5f,0.5f,-0.5f,-0.5f,0.5f};
    const float sz[8] = {-0.5f,-0.5f,-0.5f,-0.5f,0.5f,0.5f,0.5f,0.5f};
    float c = __builtin_cosf(b[6]), s = __builtin_sinf(b[6]);
#pragma unroll
    for (int k = 0; k < 8; k++) {
        float x = b[5] * sx[k], y = b[4] * sy[k], z = b[3] * sz[k];
        cx[k] = x * c - y * s + b[0];
        cy[k] = x * s + y * c + b[1];
        cz[k] = z + b[2];
    }
}

__device__ __forceinline__ void proj_T(const float* __restrict__ T, float cx[8], float cy[8], float cz[8]) {
#pragma unroll
    for (int k = 0; k < 8; k++) {
        float x = cx[k], y = cy[k], z = cz[k];
        cx[k] = T[0] * x + T[1] * y + T[2]  * z + T[3];
        cy[k] = T[4] * x + T[5] * y + T[6]  * z + T[7];
        cz[k] = T[8] * x + T[9] * y + T[10] * z + T[11];
    }
}

__device__ __forceinline__ void corner_to_center(const float cx[8], const float cy[8], const float cz[8], float b[7]) {
    float mx = 0.f, my = 0.f, mz = 0.f;
#pragma unroll
    for (int k = 0; k < 8; k++) { mx += cx[k]; my += cy[k]; mz += cz[k]; }
    mx *= 0.125f; my *= 0.125f; mz *= 0.125f;
    float htop = (cz[4] + cz[5] + cz[6] + cz[7]) * 0.25f;
    float hbot = (cz[0] + cz[1] + cz[2] + cz[3]) * 0.25f;
    const int lA[4] = {0,1,4,5}, lB[4] = {3,2,7,6};
    const int wA[4] = {0,3,4,7}, wB[4] = {1,2,5,6};
    float l = 0.f, w = 0.f, dx = 0.f, dy = 0.f;
#pragma unroll
    for (int i = 0; i < 4; i++) {
        float ax = cx[lA[i]] - cx[lB[i]];
        float ay = cy[lA[i]] - cy[lB[i]];
        l += __builtin_sqrtf(ax * ax + ay * ay);
        dx += ax; dy += ay;
    }
#pragma unroll
    for (int i = 0; i < 4; i++) {
        float ax = cx[wA[i]] - cx[wB[i]];
        float ay = cy[wA[i]] - cy[wB[i]];
        w += __builtin_sqrtf(ax * ax + ay * ay);
    }
    b[0] = mx; b[1] = my; b[2] = mz;
    b[3] = htop - hbot;
    b[4] = w * 0.25f;
    b[5] = l * 0.25f;
    b[6] = atan2f(dy, dx);
}

// ---------------- K7: decode selected boxes -> out corners + standup ----------------
__global__ void __launch_bounds__(256) k_boxes(const float* __restrict__ anchors,
                                               const float* __restrict__ psm_v,
                                               const float* __restrict__ psm_i,
                                               const float* __restrict__ rm_v,
                                               const float* __restrict__ rm_i,
                                               const float* __restrict__ tproj,
                                               const float* __restrict__ tego,
                                               const u32* __restrict__ sel_idx,
                                               float* __restrict__ sel_sc,
                                               float* __restrict__ out,
                                               float4* __restrict__ stand) {
    int k = blockIdx.x * blockDim.x + threadIdx.x;
    if (k >= TOPK) return;
    int n = (int)(sel_idx[k] & (u32)(NT - 1));   // defensive mask; identity when valid
    int br = n >> 18;
    int m  = n & (N2 - 1);
    int a  = m & 1;
    int hw = m >> 1;

    // masked score (for NMS valid + final column)
    const float* psm = br ? psm_i : psm_v;
    float xs = psm[a * HW + hw];
    float s  = 1.0f / (1.0f + __builtin_expf(-xs));
    sel_sc[k] = (s > SCORE_THR) ? s : -1.0f;

    // delta -> box
    const float* rm = br ? rm_i : rm_v;
    float d[7];
#pragma unroll
    for (int j = 0; j < 7; j++) d[j] = rm[(a * 7 + j) * HW + hw];
    const float* anc = anchors + (size_t)m * 7;
    float a0 = anc[0], a1 = anc[1], a2 = anc[2], a3 = anc[3], a4 = anc[4], a5 = anc[5], a6 = anc[6];
    float ad = __builtin_sqrtf(a4 * a4 + a5 * a5);
    float b[7];
    b[0] = d[0] * ad + a0;
    b[1] = d[1] * ad + a1;
    b[2] = d[2] * a3 + a2;
    b[3] = __builtin_expf(d[3]) * a3;
    b[4] = __builtin_expf(d[4]) * a4;
    b[5] = __builtin_expf(d[5]) * a5;
    b[6] = d[6] + a6;

    if (br) {  // infrared branch: corners -> t_proj -> back to center form
        float cx[8], cy[8], cz[8];
        box_corners(b, cx, cy, cz);
        proj_T(tproj, cx, cy, cz);
        corner_to_center(cx, cy, cz, b);
    }

    // final corners via t_ego
    float cx[8], cy[8], cz[8];
    box_corners(b, cx, cy, cz);
    proj_T(tego, cx, cy, cz);

    float mnx = cx[0], mny = cy[0], mxx = cx[0], mxy = cy[0];
#pragma unroll
    for (int c = 0; c < 8; c++) {
        out[(size_t)k * 25 + c * 3 + 0] = cx[c];
        out[(size_t)k * 25 + c * 3 + 1] = cy[c];
        out[(size_t)k * 25 + c * 3 + 2] = cz[c];
        mnx = fminf(mnx, cx[c]); mny = fminf(mny, cy[c]);
        mxx = fmaxf(mxx, cx[c]); mxy = fmaxf(mxy, cy[c]);
    }
    stand[k] = make_float4(mnx, mny, mxx, mxy);
}

// ---------------- K8: suppression bitmask (row i x 4096 cols) ----------------
// Word-chunks w < i>>6 have j<i for all bits -> all zero; skip their compute.
__global__ void __launch_bounds__(64) k_mask(const float4* __restrict__ stand,
                                             u64* __restrict__ mask) {
    int i = blockIdx.x;
    int t = threadIdx.x;
    int w0 = i >> 6;
    float4 bi = stand[i];
    float areai = (bi.z - bi.x) * (bi.w - bi.y);
    u64 myword = 0ull;
    for (int w = w0; w < 64; ++w) {
        int j = w * 64 + t;
        float4 bj = stand[j];
        float areaj = (bj.z - bj.x) * (bj.w - bj.y);
        float ltx = fmaxf(bi.x, bj.x), lty = fmaxf(bi.y, bj.y);
        float rbx = fminf(bi.z, bj.z), rby = fminf(bi.w, bj.w);
        float iw = fmaxf(rbx - ltx, 0.0f), ih = fmaxf(rby - lty, 0.0f);
        float inter = iw * ih;
        float iou = inter / (areai + areaj - inter + 1e-6f);
        bool sup = (iou > NMS_THR) && (j > i);
        u64 bits = __ballot(sup);
        if (t == w) myword = bits;
    }
    mask[(size_t)i * 64 + t] = myword;   // coalesced row store (zeros for t<w0)
}

// ---------------- K9: 4-wave cooperative sequential greedy NMS ----------------
// 256 threads (4 waves; barrier cost ~4x cheaper than R4's 16 waves).
// Per chunk: each thread loads its 16 row-words into REGISTERS (loads cannot
// sink past __syncthreads - it is a memory fence - so they complete during
// wave 0's chain via the compiler's vmcnt(0)-before-barrier drain). Wave 0
// resolves the keep chain visiting only alive boxes (ffs loop, scalar ALU +
// readlane). After barrier: branchless register fold + LDS atomicOr.
__global__ void __launch_bounds__(256) k_nms(const u64* __restrict__ mask,
                                             const float* __restrict__ sc,
                                             float* __restrict__ out) {
    __shared__ u64 remv_sh[64];
    __shared__ u64 keep_sh[64];
    __shared__ u64 kb_sh;
    int tid = threadIdx.x;
    int w = tid >> 6, l = tid & 63;
    if (tid < 64) remv_sh[tid] = 0ull;
    u64 colB = 0ull;
    float mysc = 0.0f;
    if (w == 0) { colB = mask[(size_t)l * 64]; mysc = sc[l]; }
    __syncthreads();
    for (int B = 0; B < 64; ++B) {
        // all threads: issue this chunk's 16 row-word loads (chain-independent)
        const u64* rowp = mask + (size_t)(B * 64 + w * 16) * 64 + l;
        u64 rr[16];
#pragma unroll
        for (int k2 = 0; k2 < 16; ++k2) rr[k2] = rowp[(size_t)k2 * 64];
        u64 colB_next = 0ull;
        float sc_next = 0.0f;
        if (w == 0) {
            if (B < 63) {   // prefetch next chunk's column word + scores
                colB_next = mask[(size_t)((B + 1) * 64 + l) * 64 + (B + 1)];
                sc_next   = sc[(B + 1) * 64 + l];
            }
            u64 validm = __ballot(mysc > SCORE_THR);
            u64 curw = remv_sh[B];          // folds of chunks < B (barrier-ordered)
            u32 clo = (u32)colB, chi = (u32)(colB >> 32);
            u64 alive = validm & ~curw;     // boxes that can still be kept
            u64 kb = 0ull;
            while (alive) {                 // wave-uniform; visits only kept boxes
                int r = __builtin_ctzll(alive);
                u64 col_r = ((u64)(u32)__builtin_amdgcn_readlane((int)chi, r) << 32)
                          |  (u64)(u32)__builtin_amdgcn_readlane((int)clo, r);
                kb |= 1ull << r;
                alive &= ~(col_r | (1ull << r));  // drop r + everything it suppresses
            }
            if (l == 0) { kb_sh = kb; keep_sh[B] = kb; }
        }
        __syncthreads();     // kb_sh visible; remv_sh[B] read precedes fold writes
        u64 kb = kb_sh;
        u64 p = 0ull;
#pragma unroll
        for (int k2 = 0; k2 < 16; ++k2)
            p |= rr[k2] & (0ull - ((kb >> (w * 16 + k2)) & 1ull));
        if (p) atomicOr(&remv_sh[l], p);
        __syncthreads();     // fold(B) complete before chain reads remv_sh[B+1]
        colB = colB_next;
        mysc = sc_next;
    }
    // final score column (keep_sh complete after last barrier)
#pragma unroll
    for (int j = 0; j < 16; ++j) {
        int i = tid * 16 + j;
        float s = sc[i];
        out[(size_t)i * 25 + 24] = ((keep_sh[i >> 6] >> (i & 63)) & 1ull) ? s : 0.0f;
    }
}

extern "C" void kernel_launch(void* const* d_in, const int* in_sizes, int n_in,
                              void* d_out, int out_size, void* d_ws, size_t ws_size,
                              hipStream_t stream) {
    const float* anchors = (const float*)d_in[0];
    const float* psm_v   = (const float*)d_in[1];
    const float* rm_v    = (const float*)d_in[2];
    const float* psm_i   = (const float*)d_in[3];
    const float* rm_i    = (const float*)d_in[4];
    const float* tproj   = (const float*)d_in[5];
    const float* tego    = (const float*)d_in[6];
    float* out = (float*)d_out;
    char* ws = (char*)d_ws;

    u32*    keys    = (u32*)(ws + OFF_KEYS);
    u64*    mask    = (u64*)(ws + OFF_KEYS);    // reuse after keys are consumed
    u64*    cand    = (u64*)(ws + OFF_CAND);
    u32*    hist1   = (u32*)(ws + OFF_HIST1);
    u32*    hist2   = (u32*)(ws + OFF_HIST2);
    u32*    cnt     = (u32*)(ws + OFF_CNT);
    u32*    pivot   = (u32*)(ws + OFF_PIVOT);
    u32*    sel_idx = (u32*)(ws + OFF_SELIDX);
    float*  sel_sc  = (float*)(ws + OFF_SELSC);
    float4* stand   = (float4*)(ws + OFF_STAND);

    // ws is re-poisoned to 0xAA before every launch: zero the accumulators
    hipMemsetAsync(ws + OFF_HIST1, 0, ZERO_BYTES, stream);

    k_keys   <<<NT / 1024, 1024, 0, stream>>>(psm_v, psm_i, keys, hist1);
    k_pivot  <<<1, 1024, 0, stream>>>(hist1, pivot, 0);
    k_hist2  <<<NT / 1024, 1024, 0, stream>>>(keys, pivot, hist2);
    k_pivot  <<<1, 1024, 0, stream>>>(hist2, pivot, 1);
    k_collect<<<NT / 1024, 1024, 0, stream>>>(keys, pivot, cand, cnt);
    k_rank   <<<32, 256, 0, stream>>>(cand, cnt, sel_idx);
    k_boxes  <<<TOPK / 256, 256, 0, stream>>>(anchors, psm_v, psm_i, rm_v, rm_i,
                                              tproj, tego, sel_idx, sel_sc, out, stand);
    k_mask   <<<TOPK, 64, 0, stream>>>(stand, mask);
    k_nms    <<<1, 256, 0, stream>>>(mask, sel_sc, out);
}